// Round 5
// baseline (385.846 us; speedup 1.0000x reference)
//
#include <hip/hip_runtime.h>
#include <math.h>

#define N_NODES 100000
#define N_EDGES 1600000
#define OUT_F   64
#define SCAN_B  1024
#define NBLK    ((N_NODES + SCAN_B - 1) / SCAN_B)   // 98

#define EQ4      (N_EDGES / 4)                       // 400000 quads
#define HIST_BLK ((EQ4 + 255) / 256)                 // 1563
#define GEMM_BLK 512

typedef __attribute__((ext_vector_type(8))) short bf16x8;
typedef __attribute__((ext_vector_type(4))) float f32x4;

__device__ __forceinline__ unsigned short f2bf_rne(float f) {
    unsigned u = __float_as_uint(f);
    return (unsigned short)((u + 0x7fffu + ((u >> 16) & 1u)) >> 16);
}
__device__ __forceinline__ float bf2f(unsigned short h) {
    return __uint_as_float((unsigned)h << 16);
}

// ---------------------------------------------------------------------------
// hist + GEMM fused.
// hist blocks [0, HIST_BLK): per-edge returning atomics into deg_p, which is
//   PADDED to one counter per 64B line (node*16) — R4 showed 102 µs with
//   VALU 0.3%: 1.6M RMWs serialized over 6250 lines. Padding spreads them
//   over 100K lines (16 RMWs/line). Also LDS 98-bin chunk histogram -> bsum
//   (replaces scanA).
// GEMM blocks [HIST_BLK, +GEMM_BLK): G = feat @ W_h via MFMA (3-term bf16
//   split) — hides under the hist atomic stalls (R3-proven placement).
// ---------------------------------------------------------------------------
__global__ __launch_bounds__(256) void hist_gemm(
    const int* __restrict__ dst,
    unsigned* __restrict__ deg_p,          // stride-16 padded counters
    unsigned short* __restrict__ pos, unsigned* __restrict__ bsum,
    const float* __restrict__ feat, const float* __restrict__ weight,
    unsigned short* __restrict__ G)
{
    int tid = threadIdx.x;

    if (blockIdx.x < HIST_BLK) {
        __shared__ unsigned lbin[NBLK];
        if (tid < NBLK) lbin[tid] = 0u;
        __syncthreads();

        int q = blockIdx.x * 256 + tid;
        if (q < EQ4) {
            int4 d = ((const int4*)dst)[q];
            ushort4 p;
            p.x = (unsigned short)atomicAdd(&deg_p[(unsigned)d.x << 4], 1u);
            p.y = (unsigned short)atomicAdd(&deg_p[(unsigned)d.y << 4], 1u);
            p.z = (unsigned short)atomicAdd(&deg_p[(unsigned)d.z << 4], 1u);
            p.w = (unsigned short)atomicAdd(&deg_p[(unsigned)d.w << 4], 1u);
            ((ushort4*)pos)[q] = p;
            atomicAdd(&lbin[d.x >> 10], 1u);
            atomicAdd(&lbin[d.y >> 10], 1u);
            atomicAdd(&lbin[d.z >> 10], 1u);
            atomicAdd(&lbin[d.w >> 10], 1u);
        }
        __syncthreads();
        if (tid < NBLK) {
            unsigned v = lbin[tid];
            if (v) atomicAdd(&bsum[tid], v);
        }
        return;
    }

    // ---- MFMA GEMM: D[i=out_feat][j=node] ----
    int gb = (int)blockIdx.x - HIST_BLK;
    int wv = tid >> 6, ln = tid & 63;
    int li = ln & 15, lk = ln >> 4;

    bf16x8 Whi[4][2], Wlo[4][2];
    #pragma unroll
    for (int it = 0; it < 4; ++it)
        #pragma unroll
        for (int kb = 0; kb < 2; ++kb)
            #pragma unroll
            for (int j = 0; j < 8; ++j) {
                float w = weight[(16 + kb * 32 + lk * 8 + j) * 64 + it * 16 + li];
                unsigned short h = f2bf_rne(w);
                Whi[it][kb][j] = (short)h;
                Wlo[it][kb][j] = (short)f2bf_rne(w - bf2f(h));
            }

    const int tiles = N_NODES / 16;   // 6250 exact
    for (int tile = gb * 4 + wv; tile < tiles; tile += GEMM_BLK * 4) {
        int n = tile * 16 + li;
        const float* fr = feat + (size_t)n * 64 + lk * 8;

        bf16x8 Bhi[2], Blo[2];
        #pragma unroll
        for (int kb = 0; kb < 2; ++kb) {
            float4 v0 = *(const float4*)(fr + kb * 32);
            float4 v1 = *(const float4*)(fr + kb * 32 + 4);
            float vv[8] = {v0.x, v0.y, v0.z, v0.w, v1.x, v1.y, v1.z, v1.w};
            #pragma unroll
            for (int j = 0; j < 8; ++j) {
                unsigned short h = f2bf_rne(vv[j]);
                Bhi[kb][j] = (short)h;
                Blo[kb][j] = (short)f2bf_rne(vv[j] - bf2f(h));
            }
        }

        f32x4 acc[4] = {{0.f,0.f,0.f,0.f},{0.f,0.f,0.f,0.f},
                        {0.f,0.f,0.f,0.f},{0.f,0.f,0.f,0.f}};
        #pragma unroll
        for (int kb = 0; kb < 2; ++kb)
            #pragma unroll
            for (int it = 0; it < 4; ++it) {
                acc[it] = __builtin_amdgcn_mfma_f32_16x16x32_bf16(Whi[it][kb], Bhi[kb], acc[it], 0, 0, 0);
                acc[it] = __builtin_amdgcn_mfma_f32_16x16x32_bf16(Wlo[it][kb], Bhi[kb], acc[it], 0, 0, 0);
                acc[it] = __builtin_amdgcn_mfma_f32_16x16x32_bf16(Whi[it][kb], Blo[kb], acc[it], 0, 0, 0);
            }

        #pragma unroll
        for (int it = 0; it < 4; ++it) {
            ushort4 o;
            o.x = f2bf_rne(acc[it][0]);
            o.y = f2bf_rne(acc[it][1]);
            o.z = f2bf_rne(acc[it][2]);
            o.w = f2bf_rne(acc[it][3]);
            *(ushort4*)(G + (size_t)n * 64 + it * 16 + lk * 4) = o;
        }
    }
}

// ---------------------------------------------------------------------------
// scanC: exclusive scan of padded deg -> off (block offset = sum of
// bsum[j<blk] computed in-block). Shuffle-based, 2 barriers.
// ---------------------------------------------------------------------------
__global__ __launch_bounds__(SCAN_B) void scanC(
    const unsigned* __restrict__ deg_p, const unsigned* __restrict__ bsum,
    unsigned* __restrict__ off)
{
    __shared__ unsigned ws[17];
    int t = threadIdx.x;

    if (t < 64) {
        unsigned a = 0u;
        for (int j = t; j < (int)blockIdx.x; j += 64) a += bsum[j];
        #pragma unroll
        for (int o = 32; o; o >>= 1) a += __shfl_down(a, o);
        if (t == 0) ws[16] = a;
    }

    int i = blockIdx.x * SCAN_B + t;
    unsigned v = (i < N_NODES) ? deg_p[(unsigned)i << 4] : 0u;
    unsigned x = v;
    #pragma unroll
    for (int o = 1; o < 64; o <<= 1) {
        unsigned u = __shfl_up(x, o);
        if ((t & 63) >= o) x += u;
    }
    if ((t & 63) == 63) ws[t >> 6] = x;
    __syncthreads();
    if (t < 16) {
        unsigned y = ws[t];
        #pragma unroll
        for (int o = 1; o < 16; o <<= 1) {
            unsigned u = __shfl_up(y, o);
            if (t >= o) y += u;
        }
        ws[t] = y;
    }
    __syncthreads();
    unsigned base = ws[16] + ((t >> 6) ? ws[(t >> 6) - 1] : 0u);
    unsigned excl = base + x - v;
    if (i < N_NODES) off[i] = excl;
    if (i == N_NODES - 1) off[N_NODES] = excl + v;
}

// ---------------------------------------------------------------------------
// fill: atomic-free scatter — slot = off[dst] + pos. 4 edges/thread.
// (Pure: the GEMM does NOT belong here — R4 measured the fusion as a net
// regression vs hiding it under hist's atomic stalls.)
// ---------------------------------------------------------------------------
__global__ __launch_bounds__(256) void fill_kernel(
    const int* __restrict__ src, const int* __restrict__ dst,
    const unsigned short* __restrict__ pos, const unsigned* __restrict__ off,
    unsigned long long* __restrict__ csr_pack)
{
    int q = blockIdx.x * 256 + threadIdx.x;
    if (q >= EQ4) return;
    int4 s = ((const int4*)src)[q];
    int4 d = ((const int4*)dst)[q];
    ushort4 p = ((const ushort4*)pos)[q];
    unsigned e = (unsigned)q * 4u;
    csr_pack[off[d.x] + (unsigned)p.x] =
        (unsigned long long)(unsigned)s.x | ((unsigned long long)(e + 0u) << 32);
    csr_pack[off[d.y] + (unsigned)p.y] =
        (unsigned long long)(unsigned)s.y | ((unsigned long long)(e + 1u) << 32);
    csr_pack[off[d.z] + (unsigned)p.z] =
        (unsigned long long)(unsigned)s.z | ((unsigned long long)(e + 2u) << 32);
    csr_pack[off[d.w] + (unsigned)p.w] =
        (unsigned long long)(unsigned)s.w | ((unsigned long long)(e + 3u) << 32);
}

// ---------------------------------------------------------------------------
// Gather + epilogue — proven R4 body (100.3-101 µs).
// ---------------------------------------------------------------------------
__global__ __launch_bounds__(256) void gather_out(
    const unsigned short* __restrict__ G,
    const float* __restrict__ edge_feats,
    const unsigned long long* __restrict__ csr_pack,
    const unsigned* __restrict__ off,
    const float* __restrict__ weight,   // rows 0..15 = W_e
    const float* __restrict__ bias,
    float* __restrict__ out)
{
    int tid = threadIdx.x;
    int wv = tid >> 6, ln = tid & 63;

    float We[16];
    #pragma unroll
    for (int k = 0; k < 16; ++k) We[k] = weight[k * 64 + ln];
    float b = bias[ln];

    const float SC = 1.0507009873554805f;
    const float AL = 1.6732632423543772f;

    int n = blockIdx.x * 4 + wv;
    if (n >= N_NODES) return;

    unsigned start = off[n], end = off[n + 1];
    float norm2 = __builtin_amdgcn_rcpf(fmaxf((float)(end - start), 1.0f));

    const int gq = ln >> 4;   // G row-group 0..3
    const int eq = ln >> 2;   // EF row-group 0..15

    float gh4[4] = {0.f, 0.f, 0.f, 0.f};
    float ae4[4] = {0.f, 0.f, 0.f, 0.f};

    const ushort4* __restrict__ Gv = (const ushort4*)G;

    for (unsigned base = start; base < end; base += 64u) {
        unsigned m = min(64u, end - base);
        unsigned lo = 0u, hi = 0u;
        if ((unsigned)ln < m) {
            unsigned long long pk = csr_pack[base + (unsigned)ln];
            lo = (unsigned)pk;
            hi = (unsigned)(pk >> 32);
        }

        for (unsigned i = 0; i < m; i += 8u) {
            unsigned i0 = i + (unsigned)gq, i1 = i0 + 4u;
            unsigned s0 = __shfl(lo, (int)min(i0, m - 1u));
            unsigned s1 = __shfl(lo, (int)min(i1, m - 1u));
            ushort4 q0 = {0,0,0,0}, q1 = {0,0,0,0};
            if (i0 < m) q0 = Gv[(size_t)s0 * 16u + (unsigned)(ln & 15)];
            if (i1 < m) q1 = Gv[(size_t)s1 * 16u + (unsigned)(ln & 15)];
            gh4[0] += __uint_as_float((unsigned)q0.x << 16) + __uint_as_float((unsigned)q1.x << 16);
            gh4[1] += __uint_as_float((unsigned)q0.y << 16) + __uint_as_float((unsigned)q1.y << 16);
            gh4[2] += __uint_as_float((unsigned)q0.z << 16) + __uint_as_float((unsigned)q1.z << 16);
            gh4[3] += __uint_as_float((unsigned)q0.w << 16) + __uint_as_float((unsigned)q1.w << 16);
        }

        for (unsigned i = 0; i < m; i += 16u) {
            unsigned ie = i + (unsigned)eq;
            unsigned e0 = __shfl(hi, (int)min(ie, m - 1u));
            if (ie < m) {
                float4 v = *(const float4*)(edge_feats + (size_t)e0 * 16u + (unsigned)(ln & 3) * 4u);
                ae4[0] += v.x; ae4[1] += v.y; ae4[2] += v.z; ae4[3] += v.w;
            }
        }
    }

    #pragma unroll
    for (int c = 0; c < 4; ++c) {
        gh4[c] += __shfl_xor(gh4[c], 16);
        gh4[c] += __shfl_xor(gh4[c], 32);
        ae4[c] += __shfl_xor(ae4[c], 4);
        ae4[c] += __shfl_xor(ae4[c], 8);
        ae4[c] += __shfl_xor(ae4[c], 16);
        ae4[c] += __shfl_xor(ae4[c], 32);
    }
    int srcl = ln >> 2;
    float r0 = __shfl(gh4[0], srcl);
    float r1 = __shfl(gh4[1], srcl);
    float r2 = __shfl(gh4[2], srcl);
    float r3 = __shfl(gh4[3], srcl);
    int c = ln & 3;
    float gh = (c & 2) ? ((c & 1) ? r3 : r2) : ((c & 1) ? r1 : r0);

    float acc = gh;
    #pragma unroll
    for (int k = 0; k < 16; ++k)
        acc = fmaf(__shfl(ae4[k & 3], k >> 2), We[k], acc);

    float o = acc * norm2 + b;
    out[(size_t)n * 64u + ln] = (o > 0.f) ? SC * o : SC * AL * (__expf(o) - 1.0f);
}

extern "C" void kernel_launch(void* const* d_in, const int* in_sizes, int n_in,
                              void* d_out, int out_size, void* d_ws, size_t ws_size,
                              hipStream_t stream) {
    const float* feat       = (const float*)d_in[0];
    const float* edge_feats = (const float*)d_in[1];
    const int*   src        = (const int*)d_in[2];
    const int*   dst        = (const int*)d_in[3];
    const float* weight     = (const float*)d_in[4];
    const float* bias       = (const float*)d_in[5];
    float* out = (float*)d_out;

    // ws layout: csr_pack 12.8MB (first 6.4MB aliased by deg_p: deg_p dead
    // before fill writes csr_pack) | G 12.8MB | pos 3.2MB | off(+1) | bsum
    unsigned long long* csr_pack = (unsigned long long*)d_ws;
    unsigned* deg_p = (unsigned*)d_ws;               // stride-16 (64B/counter)
    unsigned short* G   = (unsigned short*)(csr_pack + N_EDGES);
    unsigned short* pos = G + (size_t)N_NODES * 64;
    unsigned* off   = (unsigned*)(pos + N_EDGES);    // N_NODES + 1
    unsigned* bsum  = off + N_NODES + 1;             // NBLK

    hipMemsetAsync(deg_p, 0, (size_t)N_NODES * 16 * sizeof(unsigned), stream);
    hipMemsetAsync(bsum, 0, NBLK * sizeof(unsigned), stream);
    hist_gemm<<<dim3(HIST_BLK + GEMM_BLK), dim3(256), 0, stream>>>(
        dst, deg_p, pos, bsum, feat, weight, G);
    scanC<<<dim3(NBLK), dim3(SCAN_B), 0, stream>>>(deg_p, bsum, off);
    fill_kernel<<<dim3(HIST_BLK), dim3(256), 0, stream>>>(
        src, dst, pos, off, csr_pack);
    gather_out<<<dim3((N_NODES + 3) / 4), dim3(256), 0, stream>>>(
        G, edge_feats, csr_pack, off, weight, bias, out);
}

// Round 6
// 370.170 us; speedup vs baseline: 1.0423x; 1.0423x over previous
//
#include <hip/hip_runtime.h>
#include <math.h>

#define N_NODES 100000
#define N_EDGES 1600000
#define OUT_F   64
#define NCHUNK  98                      // ceil(N_NODES / 1024)

#define EQ4      (N_EDGES / 4)          // 400000 quads
#define CNT_BLK  ((EQ4 + 255) / 256)    // 1563
#define GEMM_BLK 512
#define K_E      18                     // max 18432 edges/chunk (mean 16384, 16 sigma)

typedef __attribute__((ext_vector_type(8))) short bf16x8;
typedef __attribute__((ext_vector_type(4))) float f32x4;

__device__ __forceinline__ unsigned short f2bf_rne(float f) {
    unsigned u = __float_as_uint(f);
    return (unsigned short)((u + 0x7fffu + ((u >> 16) & 1u)) >> 16);
}
__device__ __forceinline__ float bf2f(unsigned short h) {
    return __uint_as_float((unsigned)h << 16);
}

// ---------------------------------------------------------------------------
// K1: blocks [0, CNT_BLK): LDS 98-bin histogram of dst>>10 -> bsum.
//     (No per-edge global atomics, no pos array — ranks come later from LDS.)
//     blocks [CNT_BLK, +GEMM_BLK): G = feat @ W_h via MFMA (3-term bf16
//     split, f32-accurate) — R3-proven placement under the light hist.
// ---------------------------------------------------------------------------
__global__ __launch_bounds__(256) void count_gemm(
    const int* __restrict__ dst, unsigned* __restrict__ bsum,
    const float* __restrict__ feat, const float* __restrict__ weight,
    unsigned short* __restrict__ G)
{
    __shared__ unsigned lbin[NCHUNK];
    int tid = threadIdx.x;

    if (blockIdx.x < CNT_BLK) {
        if (tid < NCHUNK) lbin[tid] = 0u;
        __syncthreads();
        int q = blockIdx.x * 256 + tid;
        if (q < EQ4) {
            int4 d = ((const int4*)dst)[q];
            atomicAdd(&lbin[d.x >> 10], 1u);
            atomicAdd(&lbin[d.y >> 10], 1u);
            atomicAdd(&lbin[d.z >> 10], 1u);
            atomicAdd(&lbin[d.w >> 10], 1u);
        }
        __syncthreads();
        if (tid < NCHUNK) {
            unsigned v = lbin[tid];
            if (v) atomicAdd(&bsum[tid], v);
        }
        return;
    }

    // ---- MFMA GEMM: D[i=out_feat][j=node] ----
    int gb = (int)blockIdx.x - CNT_BLK;
    int wv = tid >> 6, ln = tid & 63;
    int li = ln & 15, lk = ln >> 4;

    bf16x8 Whi[4][2], Wlo[4][2];
    #pragma unroll
    for (int it = 0; it < 4; ++it)
        #pragma unroll
        for (int kb = 0; kb < 2; ++kb)
            #pragma unroll
            for (int j = 0; j < 8; ++j) {
                float w = weight[(16 + kb * 32 + lk * 8 + j) * 64 + it * 16 + li];
                unsigned short h = f2bf_rne(w);
                Whi[it][kb][j] = (short)h;
                Wlo[it][kb][j] = (short)f2bf_rne(w - bf2f(h));
            }

    const int tiles = N_NODES / 16;   // 6250 exact
    for (int tile = gb * 4 + wv; tile < tiles; tile += GEMM_BLK * 4) {
        int n = tile * 16 + li;
        const float* fr = feat + (size_t)n * 64 + lk * 8;

        bf16x8 Bhi[2], Blo[2];
        #pragma unroll
        for (int kb = 0; kb < 2; ++kb) {
            float4 v0 = *(const float4*)(fr + kb * 32);
            float4 v1 = *(const float4*)(fr + kb * 32 + 4);
            float vv[8] = {v0.x, v0.y, v0.z, v0.w, v1.x, v1.y, v1.z, v1.w};
            #pragma unroll
            for (int j = 0; j < 8; ++j) {
                unsigned short h = f2bf_rne(vv[j]);
                Bhi[kb][j] = (short)h;
                Blo[kb][j] = (short)f2bf_rne(vv[j] - bf2f(h));
            }
        }

        f32x4 acc[4] = {{0.f,0.f,0.f,0.f},{0.f,0.f,0.f,0.f},
                        {0.f,0.f,0.f,0.f},{0.f,0.f,0.f,0.f}};
        #pragma unroll
        for (int kb = 0; kb < 2; ++kb)
            #pragma unroll
            for (int it = 0; it < 4; ++it) {
                acc[it] = __builtin_amdgcn_mfma_f32_16x16x32_bf16(Whi[it][kb], Bhi[kb], acc[it], 0, 0, 0);
                acc[it] = __builtin_amdgcn_mfma_f32_16x16x32_bf16(Wlo[it][kb], Bhi[kb], acc[it], 0, 0, 0);
                acc[it] = __builtin_amdgcn_mfma_f32_16x16x32_bf16(Whi[it][kb], Blo[kb], acc[it], 0, 0, 0);
            }

        #pragma unroll
        for (int it = 0; it < 4; ++it) {
            ushort4 o;
            o.x = f2bf_rne(acc[it][0]);
            o.y = f2bf_rne(acc[it][1]);
            o.z = f2bf_rne(acc[it][2]);
            o.w = f2bf_rne(acc[it][3]);
            *(ushort4*)(G + (size_t)n * 64 + it * 16 + lk * 4) = o;
        }
    }
}

// ---------------------------------------------------------------------------
// K2: bucket scatter. Per block: LDS ranks within each of 98 dst-chunks
// (returning LDS atomics), one returning GLOBAL atomic per non-empty chunk
// per block reserves a contiguous segment, edges stored clustered (~84B
// segments) into their chunk's region. Entry: lo = src | (dst&1023)<<20,
// hi = edge_id.
// ---------------------------------------------------------------------------
__global__ __launch_bounds__(256) void bucket_scatter(
    const int* __restrict__ src, const int* __restrict__ dst,
    const unsigned* __restrict__ bsum, unsigned* __restrict__ cursor,
    unsigned long long* __restrict__ csr_pack)
{
    __shared__ unsigned ob[128], bb[128];   // bsum originals, inclusive scan
    __shared__ unsigned cnt[NCHUNK];        // per-block chunk counts / ranks
    __shared__ unsigned gb[NCHUNK];         // reserved absolute base per chunk
    int tid = threadIdx.x;

    if (tid < 128) {
        unsigned v = (tid < NCHUNK) ? bsum[tid] : 0u;
        ob[tid] = v; bb[tid] = v;
    }
    if (tid < NCHUNK) cnt[tid] = 0u;
    __syncthreads();
    #pragma unroll
    for (int o = 1; o < 128; o <<= 1) {
        unsigned u = (tid < 128 && tid >= o) ? bb[tid - o] : 0u;
        __syncthreads();
        if (tid < 128) bb[tid] += u;
        __syncthreads();
    }

    int q = blockIdx.x * 256 + tid;
    bool act = q < EQ4;
    int4 d = {0,0,0,0}, s = {0,0,0,0};
    unsigned r0 = 0, r1 = 0, r2 = 0, r3 = 0;
    if (act) {
        d = ((const int4*)dst)[q];
        s = ((const int4*)src)[q];
        r0 = atomicAdd(&cnt[d.x >> 10], 1u);
        r1 = atomicAdd(&cnt[d.y >> 10], 1u);
        r2 = atomicAdd(&cnt[d.z >> 10], 1u);
        r3 = atomicAdd(&cnt[d.w >> 10], 1u);
    }
    __syncthreads();
    if (tid < NCHUNK) {
        unsigned c = cnt[tid];
        unsigned res = c ? atomicAdd(&cursor[tid], c) : 0u;
        gb[tid] = res + bb[tid] - ob[tid];   // absolute segment base
    }
    __syncthreads();
    if (act) {
        unsigned e = (unsigned)q * 4u;
        csr_pack[gb[d.x >> 10] + r0] =
            (unsigned long long)((unsigned)s.x | (((unsigned)d.x & 1023u) << 20))
            | ((unsigned long long)(e + 0u) << 32);
        csr_pack[gb[d.y >> 10] + r1] =
            (unsigned long long)((unsigned)s.y | (((unsigned)d.y & 1023u) << 20))
            | ((unsigned long long)(e + 1u) << 32);
        csr_pack[gb[d.z >> 10] + r2] =
            (unsigned long long)((unsigned)s.z | (((unsigned)d.z & 1023u) << 20))
            | ((unsigned long long)(e + 2u) << 32);
        csr_pack[gb[d.w >> 10] + r3] =
            (unsigned long long)((unsigned)s.w | (((unsigned)d.w & 1023u) << 20))
            | ((unsigned long long)(e + 3u) << 32);
    }
}

// ---------------------------------------------------------------------------
// K3: per-chunk CSR build. One 1024-thread block per 1024-node chunk:
// coalesced read of the chunk's edges (held in regs), per-node rank via
// returning LDS atomics, LDS scan -> off (coalesced write), in-place
// permutation within the chunk's contiguous (L2-resident, <=144KB) region.
// Entries rewritten clean: lo = src, hi = edge_id (gather unchanged).
// ---------------------------------------------------------------------------
__global__ __launch_bounds__(1024) void chunk_build(
    const unsigned* __restrict__ bsum, unsigned* __restrict__ off,
    unsigned long long* __restrict__ csr_pack)
{
    __shared__ unsigned ob[128], bb[128];
    __shared__ unsigned cnt[1024];
    __shared__ unsigned ws[16];
    int t = threadIdx.x, c = blockIdx.x;

    if (t < 128) {
        unsigned v = (t < NCHUNK) ? bsum[t] : 0u;
        ob[t] = v; bb[t] = v;
    }
    cnt[t] = 0u;
    __syncthreads();
    #pragma unroll
    for (int o = 1; o < 128; o <<= 1) {
        unsigned u = (t < 128 && t >= o) ? bb[t - o] : 0u;
        __syncthreads();
        if (t < 128) bb[t] += u;
        __syncthreads();
    }
    unsigned base = bb[c] - ob[c];   // chunk's first slot in csr_pack
    unsigned ne   = ob[c];           // edges in this chunk
    __syncthreads();

    // phase 1: coalesced read + rank via returning LDS atomics
    unsigned long long ev[K_E];
    unsigned rk[K_E];
    #pragma unroll
    for (int k = 0; k < K_E; ++k) {
        unsigned i = (unsigned)t + (unsigned)k * 1024u;
        if (i < ne) {
            ev[k] = csr_pack[base + i];
            rk[k] = atomicAdd(&cnt[(unsigned)(ev[k] >> 20) & 1023u], 1u);
        }
    }
    __syncthreads();

    // phase 2: exclusive scan of per-node counts (1024 entries, 16 waves)
    unsigned v = cnt[t];
    unsigned x = v;
    #pragma unroll
    for (int o = 1; o < 64; o <<= 1) {
        unsigned u = __shfl_up(x, o);
        if ((t & 63) >= o) x += u;
    }
    if ((t & 63) == 63) ws[t >> 6] = x;
    __syncthreads();
    if (t < 16) {
        unsigned y = ws[t];
        #pragma unroll
        for (int o = 1; o < 16; o <<= 1) {
            unsigned u = __shfl_up(y, o);
            if (t >= o) y += u;
        }
        ws[t] = y;
    }
    __syncthreads();
    unsigned excl = ((t >> 6) ? ws[(t >> 6) - 1] : 0u) + x - v;

    int gnode = c * 1024 + t;
    if (gnode < N_NODES) off[gnode] = base + excl;
    if (c == NCHUNK - 1 && t == 0) off[N_NODES] = N_EDGES;

    __syncthreads();
    cnt[t] = base + excl;            // absolute slot base per local node
    __syncthreads();

    // phase 3: in-place scatter (all reads completed in phase 1)
    #pragma unroll
    for (int k = 0; k < K_E; ++k) {
        unsigned i = (unsigned)t + (unsigned)k * 1024u;
        if (i < ne) {
            unsigned dl = (unsigned)(ev[k] >> 20) & 1023u;
            csr_pack[cnt[dl] + rk[k]] = ev[k] & 0xFFFFFFFF000FFFFFull;
        }
    }
}

// ---------------------------------------------------------------------------
// Gather + epilogue — proven R4/R5 body (100.2-101 µs), UNCHANGED.
// ---------------------------------------------------------------------------
__global__ __launch_bounds__(256) void gather_out(
    const unsigned short* __restrict__ G,
    const float* __restrict__ edge_feats,
    const unsigned long long* __restrict__ csr_pack,
    const unsigned* __restrict__ off,
    const float* __restrict__ weight,   // rows 0..15 = W_e
    const float* __restrict__ bias,
    float* __restrict__ out)
{
    int tid = threadIdx.x;
    int wv = tid >> 6, ln = tid & 63;

    float We[16];
    #pragma unroll
    for (int k = 0; k < 16; ++k) We[k] = weight[k * 64 + ln];
    float b = bias[ln];

    const float SC = 1.0507009873554805f;
    const float AL = 1.6732632423543772f;

    int n = blockIdx.x * 4 + wv;
    if (n >= N_NODES) return;

    unsigned start = off[n], end = off[n + 1];
    float norm2 = __builtin_amdgcn_rcpf(fmaxf((float)(end - start), 1.0f));

    const int gq = ln >> 4;   // G row-group 0..3
    const int eq = ln >> 2;   // EF row-group 0..15

    float gh4[4] = {0.f, 0.f, 0.f, 0.f};
    float ae4[4] = {0.f, 0.f, 0.f, 0.f};

    const ushort4* __restrict__ Gv = (const ushort4*)G;

    for (unsigned base = start; base < end; base += 64u) {
        unsigned m = min(64u, end - base);
        unsigned lo = 0u, hi = 0u;
        if ((unsigned)ln < m) {
            unsigned long long pk = csr_pack[base + (unsigned)ln];
            lo = (unsigned)pk;
            hi = (unsigned)(pk >> 32);
        }

        for (unsigned i = 0; i < m; i += 8u) {
            unsigned i0 = i + (unsigned)gq, i1 = i0 + 4u;
            unsigned s0 = __shfl(lo, (int)min(i0, m - 1u));
            unsigned s1 = __shfl(lo, (int)min(i1, m - 1u));
            ushort4 q0 = {0,0,0,0}, q1 = {0,0,0,0};
            if (i0 < m) q0 = Gv[(size_t)s0 * 16u + (unsigned)(ln & 15)];
            if (i1 < m) q1 = Gv[(size_t)s1 * 16u + (unsigned)(ln & 15)];
            gh4[0] += __uint_as_float((unsigned)q0.x << 16) + __uint_as_float((unsigned)q1.x << 16);
            gh4[1] += __uint_as_float((unsigned)q0.y << 16) + __uint_as_float((unsigned)q1.y << 16);
            gh4[2] += __uint_as_float((unsigned)q0.z << 16) + __uint_as_float((unsigned)q1.z << 16);
            gh4[3] += __uint_as_float((unsigned)q0.w << 16) + __uint_as_float((unsigned)q1.w << 16);
        }

        for (unsigned i = 0; i < m; i += 16u) {
            unsigned ie = i + (unsigned)eq;
            unsigned e0 = __shfl(hi, (int)min(ie, m - 1u));
            if (ie < m) {
                float4 v = *(const float4*)(edge_feats + (size_t)e0 * 16u + (unsigned)(ln & 3) * 4u);
                ae4[0] += v.x; ae4[1] += v.y; ae4[2] += v.z; ae4[3] += v.w;
            }
        }
    }

    #pragma unroll
    for (int c = 0; c < 4; ++c) {
        gh4[c] += __shfl_xor(gh4[c], 16);
        gh4[c] += __shfl_xor(gh4[c], 32);
        ae4[c] += __shfl_xor(ae4[c], 4);
        ae4[c] += __shfl_xor(ae4[c], 8);
        ae4[c] += __shfl_xor(ae4[c], 16);
        ae4[c] += __shfl_xor(ae4[c], 32);
    }
    int srcl = ln >> 2;
    float r0 = __shfl(gh4[0], srcl);
    float r1 = __shfl(gh4[1], srcl);
    float r2 = __shfl(gh4[2], srcl);
    float r3 = __shfl(gh4[3], srcl);
    int c = ln & 3;
    float gh = (c & 2) ? ((c & 1) ? r3 : r2) : ((c & 1) ? r1 : r0);

    float acc = gh;
    #pragma unroll
    for (int k = 0; k < 16; ++k)
        acc = fmaf(__shfl(ae4[k & 3], k >> 2), We[k], acc);

    float o = acc * norm2 + b;
    out[(size_t)n * 64u + ln] = (o > 0.f) ? SC * o : SC * AL * (__expf(o) - 1.0f);
}

extern "C" void kernel_launch(void* const* d_in, const int* in_sizes, int n_in,
                              void* d_out, int out_size, void* d_ws, size_t ws_size,
                              hipStream_t stream) {
    const float* feat       = (const float*)d_in[0];
    const float* edge_feats = (const float*)d_in[1];
    const int*   src        = (const int*)d_in[2];
    const int*   dst        = (const int*)d_in[3];
    const float* weight     = (const float*)d_in[4];
    const float* bias       = (const float*)d_in[5];
    float* out = (float*)d_out;

    // ws: csr_pack 12.8MB | G 12.8MB | off(N+1) | bsum[98] | cursor[98]
    unsigned long long* csr_pack = (unsigned long long*)d_ws;
    unsigned short* G = (unsigned short*)(csr_pack + N_EDGES);
    unsigned* off    = (unsigned*)(G + (size_t)N_NODES * 64);   // N_NODES + 1
    unsigned* bsum   = off + N_NODES + 1;                       // NCHUNK
    unsigned* cursor = bsum + NCHUNK;                           // NCHUNK

    hipMemsetAsync(bsum, 0, 2 * NCHUNK * sizeof(unsigned), stream);
    count_gemm<<<dim3(CNT_BLK + GEMM_BLK), dim3(256), 0, stream>>>(
        dst, bsum, feat, weight, G);
    bucket_scatter<<<dim3(CNT_BLK), dim3(256), 0, stream>>>(
        src, dst, bsum, cursor, csr_pack);
    chunk_build<<<dim3(NCHUNK), dim3(1024), 0, stream>>>(bsum, off, csr_pack);
    gather_out<<<dim3((N_NODES + 3) / 4), dim3(256), 0, stream>>>(
        G, edge_feats, csr_pack, off, weight, bias, out);
}

// Round 7
// 297.606 us; speedup vs baseline: 1.2965x; 1.2438x over previous
//
#include <hip/hip_runtime.h>
#include <math.h>

#define N_NODES 100000
#define N_EDGES 1600000
#define OUT_F   64
#define NCHUNK  98                      // ceil(N_NODES / 1024)

#define EQ4      (N_EDGES / 4)          // 400000 quads
#define CNT_BLK  ((EQ4 + 255) / 256)    // 1563
#define GEMM_BLK 512
#define K_E      18                     // max 18432 edges/chunk (mean 16384, +16 sigma)

typedef __attribute__((ext_vector_type(8))) short bf16x8;
typedef __attribute__((ext_vector_type(4))) float f32x4;

__device__ __forceinline__ unsigned short f2bf_rne(float f) {
    unsigned u = __float_as_uint(f);
    return (unsigned short)((u + 0x7fffu + ((u >> 16) & 1u)) >> 16);
}
__device__ __forceinline__ float bf2f(unsigned short h) {
    return __uint_as_float((unsigned)h << 16);
}

// ---------------------------------------------------------------------------
// K1: blocks [0, CNT_BLK): LDS 98-bin histogram of dst>>10, PLAIN-STORED to
//     pcnt[block][chunk] — zero global atomics (R6 suspect: 153K contended
//     RMWs on 7 lines). blocks [CNT_BLK, +GEMM_BLK): G = feat @ W_h via MFMA.
// ---------------------------------------------------------------------------
__global__ __launch_bounds__(256) void count_gemm(
    const int* __restrict__ dst, unsigned* __restrict__ pcnt,
    const float* __restrict__ feat, const float* __restrict__ weight,
    unsigned short* __restrict__ G)
{
    __shared__ unsigned lbin[NCHUNK];
    int tid = threadIdx.x;

    if (blockIdx.x < CNT_BLK) {
        if (tid < NCHUNK) lbin[tid] = 0u;
        __syncthreads();
        int q = blockIdx.x * 256 + tid;
        if (q < EQ4) {
            int4 d = ((const int4*)dst)[q];
            atomicAdd(&lbin[d.x >> 10], 1u);
            atomicAdd(&lbin[d.y >> 10], 1u);
            atomicAdd(&lbin[d.z >> 10], 1u);
            atomicAdd(&lbin[d.w >> 10], 1u);
        }
        __syncthreads();
        if (tid < NCHUNK)
            pcnt[(size_t)blockIdx.x * NCHUNK + tid] = lbin[tid];
        return;
    }

    // ---- MFMA GEMM: D[i=out_feat][j=node], 3-term bf16 split ----
    int gb = (int)blockIdx.x - CNT_BLK;
    int wv = tid >> 6, ln = tid & 63;
    int li = ln & 15, lk = ln >> 4;

    bf16x8 Whi[4][2], Wlo[4][2];
    #pragma unroll
    for (int it = 0; it < 4; ++it)
        #pragma unroll
        for (int kb = 0; kb < 2; ++kb)
            #pragma unroll
            for (int j = 0; j < 8; ++j) {
                float w = weight[(16 + kb * 32 + lk * 8 + j) * 64 + it * 16 + li];
                unsigned short h = f2bf_rne(w);
                Whi[it][kb][j] = (short)h;
                Wlo[it][kb][j] = (short)f2bf_rne(w - bf2f(h));
            }

    const int tiles = N_NODES / 16;   // 6250 exact
    for (int tile = gb * 4 + wv; tile < tiles; tile += GEMM_BLK * 4) {
        int n = tile * 16 + li;
        const float* fr = feat + (size_t)n * 64 + lk * 8;

        bf16x8 Bhi[2], Blo[2];
        #pragma unroll
        for (int kb = 0; kb < 2; ++kb) {
            float4 v0 = *(const float4*)(fr + kb * 32);
            float4 v1 = *(const float4*)(fr + kb * 32 + 4);
            float vv[8] = {v0.x, v0.y, v0.z, v0.w, v1.x, v1.y, v1.z, v1.w};
            #pragma unroll
            for (int j = 0; j < 8; ++j) {
                unsigned short h = f2bf_rne(vv[j]);
                Bhi[kb][j] = (short)h;
                Blo[kb][j] = (short)f2bf_rne(vv[j] - bf2f(h));
            }
        }

        f32x4 acc[4] = {{0.f,0.f,0.f,0.f},{0.f,0.f,0.f,0.f},
                        {0.f,0.f,0.f,0.f},{0.f,0.f,0.f,0.f}};
        #pragma unroll
        for (int kb = 0; kb < 2; ++kb)
            #pragma unroll
            for (int it = 0; it < 4; ++it) {
                acc[it] = __builtin_amdgcn_mfma_f32_16x16x32_bf16(Whi[it][kb], Bhi[kb], acc[it], 0, 0, 0);
                acc[it] = __builtin_amdgcn_mfma_f32_16x16x32_bf16(Wlo[it][kb], Bhi[kb], acc[it], 0, 0, 0);
                acc[it] = __builtin_amdgcn_mfma_f32_16x16x32_bf16(Whi[it][kb], Blo[kb], acc[it], 0, 0, 0);
            }

        #pragma unroll
        for (int it = 0; it < 4; ++it) {
            ushort4 o;
            o.x = f2bf_rne(acc[it][0]);
            o.y = f2bf_rne(acc[it][1]);
            o.z = f2bf_rne(acc[it][2]);
            o.w = f2bf_rne(acc[it][3]);
            *(ushort4*)(G + (size_t)n * 64 + it * 16 + lk * 4) = o;
        }
    }
}

// ---------------------------------------------------------------------------
// K2: per-chunk column scan of pcnt -> pbase (exclusive, over blocks) + ctot.
// One block per chunk; thread t holds elements 2t, 2t+1.
// ---------------------------------------------------------------------------
__global__ __launch_bounds__(1024) void colscan(
    const unsigned* __restrict__ pcnt, unsigned* __restrict__ pbase,
    unsigned* __restrict__ ctot)
{
    __shared__ unsigned ws[16];
    int c = blockIdx.x, t = threadIdx.x;
    unsigned j0 = 2u * (unsigned)t, j1 = j0 + 1u;
    unsigned v0 = (j0 < CNT_BLK) ? pcnt[(size_t)j0 * NCHUNK + c] : 0u;
    unsigned v1 = (j1 < CNT_BLK) ? pcnt[(size_t)j1 * NCHUNK + c] : 0u;
    unsigned s = v0 + v1;
    unsigned x = s;
    #pragma unroll
    for (int o = 1; o < 64; o <<= 1) {
        unsigned u = __shfl_up(x, o);
        if ((t & 63) >= o) x += u;
    }
    if ((t & 63) == 63) ws[t >> 6] = x;
    __syncthreads();
    if (t < 16) {
        unsigned y = ws[t];
        #pragma unroll
        for (int o = 1; o < 16; o <<= 1) {
            unsigned u = __shfl_up(y, o);
            if (t >= o) y += u;
        }
        ws[t] = y;
    }
    __syncthreads();
    unsigned excl = ((t >> 6) ? ws[(t >> 6) - 1] : 0u) + x - s;
    if (j0 < CNT_BLK) pbase[(size_t)j0 * NCHUNK + c] = excl;
    if (j1 < CNT_BLK) pbase[(size_t)j1 * NCHUNK + c] = excl + v0;
    if (t == 1023) ctot[c] = excl + s;
}

// ---------------------------------------------------------------------------
// K3: exclusive scan of the 98 chunk totals -> cbase. One block.
// ---------------------------------------------------------------------------
__global__ __launch_bounds__(128) void scan98(
    const unsigned* __restrict__ ctot, unsigned* __restrict__ cbase)
{
    __shared__ unsigned w0;
    int t = threadIdx.x;
    unsigned v = (t < NCHUNK) ? ctot[t] : 0u;
    unsigned x = v;
    #pragma unroll
    for (int o = 1; o < 64; o <<= 1) {
        unsigned u = __shfl_up(x, o);
        if ((t & 63) >= o) x += u;
    }
    if (t == 63) w0 = x;
    __syncthreads();
    unsigned base = (t >= 64) ? w0 : 0u;
    if (t < NCHUNK) cbase[t] = base + x - v;
}

// ---------------------------------------------------------------------------
// K4: scatter — ranks via LDS returning atomics (match pcnt counts exactly);
// segment base = cbase[chunk] + pbase[block][chunk] (deterministic, no global
// atomics, no barrier-on-atomic-return). Writes ~84B clustered segments.
// Entry: lo = src | (dst&1023)<<20, hi = edge_id.
// ---------------------------------------------------------------------------
__global__ __launch_bounds__(256) void scatter(
    const int* __restrict__ src, const int* __restrict__ dst,
    const unsigned* __restrict__ pbase, const unsigned* __restrict__ cbase,
    unsigned long long* __restrict__ csr_pack)
{
    __shared__ unsigned cnt[NCHUNK];
    __shared__ unsigned gb[NCHUNK];
    int tid = threadIdx.x;

    if (tid < NCHUNK) cnt[tid] = 0u;
    __syncthreads();

    int q = blockIdx.x * 256 + tid;
    bool act = q < EQ4;
    int4 d = {0,0,0,0}, s = {0,0,0,0};
    unsigned r0 = 0, r1 = 0, r2 = 0, r3 = 0;
    if (act) {
        d = ((const int4*)dst)[q];
        s = ((const int4*)src)[q];
        r0 = atomicAdd(&cnt[d.x >> 10], 1u);
        r1 = atomicAdd(&cnt[d.y >> 10], 1u);
        r2 = atomicAdd(&cnt[d.z >> 10], 1u);
        r3 = atomicAdd(&cnt[d.w >> 10], 1u);
    }
    if (tid < NCHUNK)
        gb[tid] = cbase[tid] + pbase[(size_t)blockIdx.x * NCHUNK + tid];
    __syncthreads();
    if (act) {
        unsigned e = (unsigned)q * 4u;
        csr_pack[gb[d.x >> 10] + r0] =
            (unsigned long long)((unsigned)s.x | (((unsigned)d.x & 1023u) << 20))
            | ((unsigned long long)(e + 0u) << 32);
        csr_pack[gb[d.y >> 10] + r1] =
            (unsigned long long)((unsigned)s.y | (((unsigned)d.y & 1023u) << 20))
            | ((unsigned long long)(e + 1u) << 32);
        csr_pack[gb[d.z >> 10] + r2] =
            (unsigned long long)((unsigned)s.z | (((unsigned)d.z & 1023u) << 20))
            | ((unsigned long long)(e + 2u) << 32);
        csr_pack[gb[d.w >> 10] + r3] =
            (unsigned long long)((unsigned)s.w | (((unsigned)d.w & 1023u) << 20))
            | ((unsigned long long)(e + 3u) << 32);
    }
}

// ---------------------------------------------------------------------------
// K5: per-chunk CSR build (as R6, minus the per-block 128-scan): coalesced
// read of the chunk's edges into regs, per-node rank via returning LDS
// atomics, LDS scan -> off (coalesced), in-place permute within the chunk's
// contiguous (<=147KB, L2-resident) region. Entries rewritten clean.
// ---------------------------------------------------------------------------
__global__ __launch_bounds__(1024) void chunk_build(
    const unsigned* __restrict__ ctot, const unsigned* __restrict__ cbase,
    unsigned* __restrict__ off, unsigned long long* __restrict__ csr_pack)
{
    __shared__ unsigned cnt[1024];
    __shared__ unsigned ws[16];
    int t = threadIdx.x, c = blockIdx.x;

    unsigned base = cbase[c];       // broadcast load
    unsigned ne   = ctot[c];
    cnt[t] = 0u;
    __syncthreads();

    // phase 1: coalesced read + rank via returning LDS atomics
    unsigned long long ev[K_E];
    unsigned rk[K_E];
    #pragma unroll
    for (int k = 0; k < K_E; ++k) {
        unsigned i = (unsigned)t + (unsigned)k * 1024u;
        if (i < ne) {
            ev[k] = csr_pack[base + i];
            rk[k] = atomicAdd(&cnt[(unsigned)(ev[k] >> 20) & 1023u], 1u);
        }
    }
    __syncthreads();

    // phase 2: exclusive scan of per-node counts (1024 entries, 16 waves)
    unsigned v = cnt[t];
    unsigned x = v;
    #pragma unroll
    for (int o = 1; o < 64; o <<= 1) {
        unsigned u = __shfl_up(x, o);
        if ((t & 63) >= o) x += u;
    }
    if ((t & 63) == 63) ws[t >> 6] = x;
    __syncthreads();
    if (t < 16) {
        unsigned y = ws[t];
        #pragma unroll
        for (int o = 1; o < 16; o <<= 1) {
            unsigned u = __shfl_up(y, o);
            if (t >= o) y += u;
        }
        ws[t] = y;
    }
    __syncthreads();
    unsigned excl = ((t >> 6) ? ws[(t >> 6) - 1] : 0u) + x - v;

    int gnode = c * 1024 + t;
    if (gnode < N_NODES) off[gnode] = base + excl;
    if (c == NCHUNK - 1 && t == 0) off[N_NODES] = N_EDGES;

    __syncthreads();
    cnt[t] = base + excl;            // absolute slot base per local node
    __syncthreads();

    // phase 3: in-place scatter (all reads completed in phase 1)
    #pragma unroll
    for (int k = 0; k < K_E; ++k) {
        unsigned i = (unsigned)t + (unsigned)k * 1024u;
        if (i < ne) {
            unsigned dl = (unsigned)(ev[k] >> 20) & 1023u;
            csr_pack[cnt[dl] + rk[k]] = ev[k] & 0xFFFFFFFF000FFFFFull;
        }
    }
}

// ---------------------------------------------------------------------------
// Gather + epilogue — proven body (100.2-101 µs), UNCHANGED.
// ---------------------------------------------------------------------------
__global__ __launch_bounds__(256) void gather_out(
    const unsigned short* __restrict__ G,
    const float* __restrict__ edge_feats,
    const unsigned long long* __restrict__ csr_pack,
    const unsigned* __restrict__ off,
    const float* __restrict__ weight,   // rows 0..15 = W_e
    const float* __restrict__ bias,
    float* __restrict__ out)
{
    int tid = threadIdx.x;
    int wv = tid >> 6, ln = tid & 63;

    float We[16];
    #pragma unroll
    for (int k = 0; k < 16; ++k) We[k] = weight[k * 64 + ln];
    float b = bias[ln];

    const float SC = 1.0507009873554805f;
    const float AL = 1.6732632423543772f;

    int n = blockIdx.x * 4 + wv;
    if (n >= N_NODES) return;

    unsigned start = off[n], end = off[n + 1];
    float norm2 = __builtin_amdgcn_rcpf(fmaxf((float)(end - start), 1.0f));

    const int gq = ln >> 4;   // G row-group 0..3
    const int eq = ln >> 2;   // EF row-group 0..15

    float gh4[4] = {0.f, 0.f, 0.f, 0.f};
    float ae4[4] = {0.f, 0.f, 0.f, 0.f};

    const ushort4* __restrict__ Gv = (const ushort4*)G;

    for (unsigned base = start; base < end; base += 64u) {
        unsigned m = min(64u, end - base);
        unsigned lo = 0u, hi = 0u;
        if ((unsigned)ln < m) {
            unsigned long long pk = csr_pack[base + (unsigned)ln];
            lo = (unsigned)pk;
            hi = (unsigned)(pk >> 32);
        }

        for (unsigned i = 0; i < m; i += 8u) {
            unsigned i0 = i + (unsigned)gq, i1 = i0 + 4u;
            unsigned s0 = __shfl(lo, (int)min(i0, m - 1u));
            unsigned s1 = __shfl(lo, (int)min(i1, m - 1u));
            ushort4 q0 = {0,0,0,0}, q1 = {0,0,0,0};
            if (i0 < m) q0 = Gv[(size_t)s0 * 16u + (unsigned)(ln & 15)];
            if (i1 < m) q1 = Gv[(size_t)s1 * 16u + (unsigned)(ln & 15)];
            gh4[0] += __uint_as_float((unsigned)q0.x << 16) + __uint_as_float((unsigned)q1.x << 16);
            gh4[1] += __uint_as_float((unsigned)q0.y << 16) + __uint_as_float((unsigned)q1.y << 16);
            gh4[2] += __uint_as_float((unsigned)q0.z << 16) + __uint_as_float((unsigned)q1.z << 16);
            gh4[3] += __uint_as_float((unsigned)q0.w << 16) + __uint_as_float((unsigned)q1.w << 16);
        }

        for (unsigned i = 0; i < m; i += 16u) {
            unsigned ie = i + (unsigned)eq;
            unsigned e0 = __shfl(hi, (int)min(ie, m - 1u));
            if (ie < m) {
                float4 v = *(const float4*)(edge_feats + (size_t)e0 * 16u + (unsigned)(ln & 3) * 4u);
                ae4[0] += v.x; ae4[1] += v.y; ae4[2] += v.z; ae4[3] += v.w;
            }
        }
    }

    #pragma unroll
    for (int c = 0; c < 4; ++c) {
        gh4[c] += __shfl_xor(gh4[c], 16);
        gh4[c] += __shfl_xor(gh4[c], 32);
        ae4[c] += __shfl_xor(ae4[c], 4);
        ae4[c] += __shfl_xor(ae4[c], 8);
        ae4[c] += __shfl_xor(ae4[c], 16);
        ae4[c] += __shfl_xor(ae4[c], 32);
    }
    int srcl = ln >> 2;
    float r0 = __shfl(gh4[0], srcl);
    float r1 = __shfl(gh4[1], srcl);
    float r2 = __shfl(gh4[2], srcl);
    float r3 = __shfl(gh4[3], srcl);
    int c = ln & 3;
    float gh = (c & 2) ? ((c & 1) ? r3 : r2) : ((c & 1) ? r1 : r0);

    float acc = gh;
    #pragma unroll
    for (int k = 0; k < 16; ++k)
        acc = fmaf(__shfl(ae4[k & 3], k >> 2), We[k], acc);

    float o = acc * norm2 + b;
    out[(size_t)n * 64u + ln] = (o > 0.f) ? SC * o : SC * AL * (__expf(o) - 1.0f);
}

extern "C" void kernel_launch(void* const* d_in, const int* in_sizes, int n_in,
                              void* d_out, int out_size, void* d_ws, size_t ws_size,
                              hipStream_t stream) {
    const float* feat       = (const float*)d_in[0];
    const float* edge_feats = (const float*)d_in[1];
    const int*   src        = (const int*)d_in[2];
    const int*   dst        = (const int*)d_in[3];
    const float* weight     = (const float*)d_in[4];
    const float* bias       = (const float*)d_in[5];
    float* out = (float*)d_out;

    // ws: csr_pack 12.8MB | G 12.8MB | off(N+1) | pcnt | pbase | ctot | cbase
    // No memsets needed: every buffer is fully written before first read.
    unsigned long long* csr_pack = (unsigned long long*)d_ws;
    unsigned short* G = (unsigned short*)(csr_pack + N_EDGES);
    unsigned* off   = (unsigned*)(G + (size_t)N_NODES * 64);    // N_NODES + 1
    unsigned* pcnt  = off + N_NODES + 1;                        // CNT_BLK*NCHUNK
    unsigned* pbase = pcnt + (size_t)CNT_BLK * NCHUNK;          // CNT_BLK*NCHUNK
    unsigned* ctot  = pbase + (size_t)CNT_BLK * NCHUNK;         // NCHUNK
    unsigned* cbase = ctot + NCHUNK;                            // NCHUNK

    count_gemm<<<dim3(CNT_BLK + GEMM_BLK), dim3(256), 0, stream>>>(
        dst, pcnt, feat, weight, G);
    colscan<<<dim3(NCHUNK), dim3(1024), 0, stream>>>(pcnt, pbase, ctot);
    scan98<<<dim3(1), dim3(128), 0, stream>>>(ctot, cbase);
    scatter<<<dim3(CNT_BLK), dim3(256), 0, stream>>>(
        src, dst, pbase, cbase, csr_pack);
    chunk_build<<<dim3(NCHUNK), dim3(1024), 0, stream>>>(
        ctot, cbase, off, csr_pack);
    gather_out<<<dim3((N_NODES + 3) / 4), dim3(256), 0, stream>>>(
        G, edge_feats, csr_pack, off, weight, bias, out);
}